// Round 14
// baseline (218.210 us; speedup 1.0000x reference)
//
#include <hip/hip_runtime.h>
#include <hip/hip_fp16.h>
#include <cstdint>
#include <cmath>

// GCN, 4 layers. Structure: A(hW) = (Ah)W with norm folded into features:
//   g = dis (.) h  stored FP16,
//   A_norm h [d] = dis[d] * ( sum_e w_e * g[src_e] + g[d] )
// CSR via two-level LDS counting sort (R12). Layers wave-autonomous (R13).
//
// R14: the agg loop's 16 VALU/edge-lane (8 cvt_f32_f16 + 8 fma) cut to 4 via
// v_pk_fma_f16 (__hfma2) with fp16 accumulators; pairs.y now stores w as a
// pre-packed half2 (converted once in bucket_csr) so the loop has zero
// conversions. Gather unroll 4 -> 8 (more MLP, no shfl). Phase-2 lane map
// flipped (node = lane>>3, slice = lane&7): wave writes contiguous rows,
// LDS row reads become broadcasts. fp16-accum error ~5e-3/layer, margin ok.

#define NPB_SHIFT 9
#define NPB 512              // nodes per bucket
#define CHUNK 4096           // edges per block in count/scatter passes

// ---- fdot2: 2x f16 MAC with fp32 accumulator (guarded builtin)
__device__ __forceinline__ float fdot2f(__half2 a, __half2 b, float c) {
#if defined(__has_builtin)
#if __has_builtin(__builtin_amdgcn_fdot2)
    typedef _Float16 h2v __attribute__((ext_vector_type(2)));
    return __builtin_amdgcn_fdot2(__builtin_bit_cast(h2v, a),
                                  __builtin_bit_cast(h2v, b), c, false);
#else
    float2 fa = __half22float2(a), fb = __half22float2(b);
    return fmaf(fa.x, fb.x, fmaf(fa.y, fb.y, c));
#endif
#else
    float2 fa = __half22float2(a), fb = __half22float2(b);
    return fmaf(fa.x, fb.x, fmaf(fa.y, fb.y, c));
#endif
}

// ---- wave-local LDS fence: all this wave's ds_writes visible to its ds_reads
__device__ __forceinline__ void wave_lds_fence() {
    asm volatile("s_waitcnt lgkmcnt(0)" ::: "memory");
    __builtin_amdgcn_wave_barrier();
    __builtin_amdgcn_sched_barrier(0);
}

// ------------------------------------------- CSR build: two-level counting sort

__global__ __launch_bounds__(256) void bucket_init_kernel(int* __restrict__ bucket_cnt,
                                                          int nbuck) {
    if ((int)threadIdx.x < nbuck) bucket_cnt[threadIdx.x] = 0;
}

__global__ __launch_bounds__(256) void bucket_count_kernel(const int* __restrict__ dst,
                                                           int* __restrict__ bucket_cnt,
                                                           int* __restrict__ blockbase,
                                                           int nbuck, int E) {
    __shared__ int hist[256];
    int tid = threadIdx.x;
    hist[tid] = 0;
    __syncthreads();
    int base = blockIdx.x * CHUNK;
    #pragma unroll
    for (int u = 0; u < CHUNK / 256; ++u) {
        int e = base + u * 256 + tid;
        if (e < E) atomicAdd(&hist[dst[e] >> NPB_SHIFT], 1);
    }
    __syncthreads();
    if (tid < nbuck)
        blockbase[blockIdx.x * nbuck + tid] = atomicAdd(&bucket_cnt[tid], hist[tid]);
}

__global__ __launch_bounds__(64) void bucket_scan_kernel(const int* __restrict__ bucket_cnt,
                                                         int* __restrict__ bucket_base,
                                                         int nbuck, int E) {
    int lane = threadIdx.x;
    int run = 0;
    for (int b0 = 0; b0 < nbuck; b0 += 64) {
        int i = b0 + lane;
        int v = (i < nbuck) ? bucket_cnt[i] : 0;
        int x = v;
        #pragma unroll
        for (int off = 1; off < 64; off <<= 1) {
            int t = __shfl_up(x, off);
            if (lane >= off) x += t;
        }
        if (i < nbuck) bucket_base[i] = run + x - v;
        run += __shfl(x, 63);
    }
    if (lane == 0) bucket_base[nbuck] = E;
}

__global__ __launch_bounds__(256) void bucket_scatter_kernel(const int* __restrict__ src,
                                                             const int* __restrict__ dst,
                                                             const float* __restrict__ w,
                                                             const int* __restrict__ bucket_base,
                                                             const int* __restrict__ blockbase,
                                                             int2* __restrict__ temp,
                                                             int nbuck, int E) {
    __shared__ int cursor[256];
    int tid = threadIdx.x;
    if (tid < nbuck)
        cursor[tid] = bucket_base[tid] + blockbase[blockIdx.x * nbuck + tid];
    __syncthreads();
    int base = blockIdx.x * CHUNK;
    #pragma unroll
    for (int u = 0; u < CHUNK / 256; ++u) {
        int e = base + u * 256 + tid;
        if (e < E) {
            int d = dst[e];
            int pos = atomicAdd(&cursor[d >> NPB_SHIFT], 1);
            temp[pos] = make_int2(src[e] | ((d & (NPB - 1)) << 17),
                                  __float_as_int(w[e]));
        }
    }
}

// final pairs: (src, w packed as half2(w,w)) -- agg loop needs no conversion
__global__ __launch_bounds__(256) void bucket_csr_kernel(const int2* __restrict__ temp,
                                                         const int* __restrict__ bucket_base,
                                                         int* __restrict__ offsets,
                                                         int2* __restrict__ pairs,
                                                         int n, int E) {
    __shared__ int cnt[NPB];
    __shared__ int wtot[4];
    int tid = threadIdx.x;
    int bk = blockIdx.x;
    int base = bucket_base[bk], end = bucket_base[bk + 1];
    cnt[tid] = 0; cnt[tid + 256] = 0;
    __syncthreads();
    for (int j = base + tid; j < end; j += 256)
        atomicAdd(&cnt[temp[j].x >> 17], 1);
    __syncthreads();
    int a0 = cnt[2 * tid], a1 = cnt[2 * tid + 1];
    int s = a0 + a1;
    int lane = tid & 63, wid = tid >> 6;
    int x = s;
    #pragma unroll
    for (int off = 1; off < 64; off <<= 1) {
        int t2 = __shfl_up(x, off);
        if (lane >= off) x += t2;
    }
    if (lane == 63) wtot[wid] = x;
    __syncthreads();
    int wbase = 0;
    #pragma unroll
    for (int wv = 0; wv < 4; ++wv) if (wv < wid) wbase += wtot[wv];
    int e0 = wbase + x - s;
    int abs0 = base + e0, abs1 = base + e0 + a0;
    int node0 = bk * NPB + 2 * tid;
    if (node0 < n)     offsets[node0]     = abs0;
    if (node0 + 1 < n) offsets[node0 + 1] = abs1;
    __syncthreads();
    cnt[2 * tid] = abs0; cnt[2 * tid + 1] = abs1;
    __syncthreads();
    for (int j = base + tid; j < end; j += 256) {
        int2 t2 = temp[j];
        int pos = atomicAdd(&cnt[t2.x >> 17], 1);
        __half2 w2 = __float2half2_rn(__int_as_float(t2.y));
        pairs[pos] = make_int2(t2.x & 0x1FFFF, *reinterpret_cast<int*>(&w2));
    }
    if (bk == 0 && tid == 0) offsets[n] = E;
}

// fused: deg row-sum -> dis -> g0 = fp16(dis (.) x). 16 lanes per node.
__global__ __launch_bounds__(256) void rowsum_scale_kernel(const int* __restrict__ offsets,
                                                           const int2* __restrict__ pairs,
                                                           const float* __restrict__ x,
                                                           float* __restrict__ dis,
                                                           __half* __restrict__ g, int n) {
    int node = blockIdx.x * 16 + (threadIdx.x >> 4);
    int q = threadIdx.x & 15;
    if (node >= n) return;
    int j0 = offsets[node], end = offsets[node + 1];
    float s = 0.f;
    for (int j = j0 + q; j < end; j += 16) {
        int wb = pairs[j].y;
        s += __low2float(*reinterpret_cast<__half2*>(&wb));
    }
    #pragma unroll
    for (int off = 8; off; off >>= 1) s += __shfl_xor(s, off);
    float dn = rsqrtf(1.0f + s);
    if (q == 0) dis[node] = dn;
    float4 v = reinterpret_cast<const float4*>(x)[(size_t)node * 16 + q];
    __half2 pk[2];
    pk[0] = __float22half2_rn(make_float2(dn * v.x, dn * v.y));
    pk[1] = __float22half2_rn(make_float2(dn * v.z, dn * v.w));
    reinterpret_cast<float2*>(g + (size_t)node * 64)[q] = *reinterpret_cast<float2*>(pk);
}

// ------------------------------------------ aggregation core (packed fp16 accum)
// 8-lane group per node; lane q owns half8 #q. acc = 4x half2, v_pk_fma_f16.
__device__ __forceinline__ void accum_pk(__half2* acc, float4 rv, int wbits) {
    __half2 w2 = *reinterpret_cast<__half2*>(&wbits);
    const __half2* h = reinterpret_cast<const __half2*>(&rv);
    acc[0] = __hfma2(w2, h[0], acc[0]);
    acc[1] = __hfma2(w2, h[1], acc[1]);
    acc[2] = __hfma2(w2, h[2], acc[2]);
    acc[3] = __hfma2(w2, h[3], acc[3]);
}

__device__ __forceinline__ void agg_node(const float4* __restrict__ gt,
                                         const int2* __restrict__ pairs,
                                         int j, int end, int node, int q,
                                         __half2* __restrict__ acc) {
    // 8-deep: 8 independent gathers in flight
    for (; j + 8 <= end; j += 8) {
        int2 p[8];
        #pragma unroll
        for (int u = 0; u < 8; ++u) p[u] = pairs[j + u];
        float4 r[8];
        #pragma unroll
        for (int u = 0; u < 8; ++u) r[u] = gt[(size_t)p[u].x * 8 + q];
        #pragma unroll
        for (int u = 0; u < 8; ++u) accum_pk(acc, r[u], p[u].y);
    }
    for (; j + 2 <= end; j += 2) {
        int2 p0 = pairs[j], p1 = pairs[j + 1];
        float4 r0 = gt[(size_t)p0.x * 8 + q];
        float4 r1 = gt[(size_t)p1.x * 8 + q];
        accum_pk(acc, r0, p0.y);
        accum_pk(acc, r1, p1.y);
    }
    if (j < end) {
        int2 p = pairs[j];
        accum_pk(acc, gt[(size_t)p.x * 8 + q], p.y);
    }
    // self term (weight 1)
    float4 rs = gt[(size_t)node * 8 + q];
    const __half2* h = reinterpret_cast<const __half2*>(&rs);
    acc[0] = __hadd2(acc[0], h[0]);
    acc[1] = __hadd2(acc[1], h[1]);
    acc[2] = __hadd2(acc[2], h[2]);
    acc[3] = __hadd2(acc[3], h[3]);
}

// ---- phase 1: wave's 8-lane group aggregates one node into rows (x dis)
__device__ __forceinline__ void phase1_agg(const __half* __restrict__ gin,
                                           const float* __restrict__ dis,
                                           const int* __restrict__ offsets,
                                           const int2* __restrict__ pairs,
                                           __half2 (*rows)[33], int n, int tid,
                                           int blockbase_node) {
    int ln = tid >> 3;
    int q  = tid & 7;
    int gnode = blockbase_node + ln;
    if (gnode < n) {
        const float4* gt = reinterpret_cast<const float4*>(gin);
        __half2 acc[4];
        acc[0] = acc[1] = acc[2] = acc[3] = __float2half2_rn(0.f);
        agg_node(gt, pairs, offsets[gnode], offsets[gnode + 1], gnode, q, acc);
        float dn = dis[gnode];
        #pragma unroll
        for (int k2 = 0; k2 < 4; ++k2) {
            float2 f = __half22float2(acc[k2]);
            rows[ln][q * 4 + k2] = __float22half2_rn(make_float2(dn * f.x, dn * f.y));
        }
    }
}

// -------------------------------- fused layer 1-3: aggregate -> GEMM64+ELU -> fp16
// Phase 2 map: node = wave*8 + (lane>>3), slice = lane&7 -> wave writes 8
// contiguous 128B rows; LDS row reads broadcast within 8-lane groups.
__global__ __launch_bounds__(256) void layer_fused_kernel(const __half* __restrict__ gin,
                                                          const float* __restrict__ dis,
                                                          const int* __restrict__ offsets,
                                                          const int2* __restrict__ pairs,
                                                          const float* __restrict__ W,
                                                          const float* __restrict__ b,
                                                          __half* __restrict__ gout, int n) {
    __shared__ __half2 rows[32][33];
    __shared__ __half2 WT[64][33];   // WT[c][k2] = (W[2k2][c], W[2k2+1][c]) fp16
    __shared__ float bias_s[64];
    for (int idx = threadIdx.x; idx < 64 * 32; idx += 256) {
        int k2 = idx >> 6, c = idx & 63;
        WT[c][k2] = __float22half2_rn(make_float2(W[(2 * k2) * 64 + c],
                                                  W[(2 * k2 + 1) * 64 + c]));
    }
    if (threadIdx.x < 64) bias_s[threadIdx.x] = b[threadIdx.x];
    __syncthreads();          // WT/bias ready (only block barrier)

    int tid = threadIdx.x;
    phase1_agg(gin, dis, offsets, pairs, rows, n, tid, blockIdx.x * 32);
    wave_lds_fence();         // this wave's rows visible to this wave

    int lane  = tid & 63, wave = tid >> 6;
    int node2 = wave * 8 + (lane >> 3);
    int slice = lane & 7;                  // outputs [8*slice, 8*slice+8)
    int gnode2 = blockIdx.x * 32 + node2;
    if (gnode2 < n) {
        __half2 h2[32];
        #pragma unroll
        for (int i = 0; i < 32; ++i) h2[i] = rows[node2][i];
        float dn = dis[gnode2];
        int c0 = slice * 8;
        float r[8];
        #pragma unroll
        for (int cc = 0; cc < 8; ++cc) {
            const __half2* wt = &WT[c0 + cc][0];
            float a0 = 0.f, a1 = 0.f, a2 = 0.f, a3 = 0.f;
            #pragma unroll
            for (int i = 0; i < 8; ++i) {
                a0 = fdot2f(h2[4 * i],     wt[4 * i],     a0);
                a1 = fdot2f(h2[4 * i + 1], wt[4 * i + 1], a1);
                a2 = fdot2f(h2[4 * i + 2], wt[4 * i + 2], a2);
                a3 = fdot2f(h2[4 * i + 3], wt[4 * i + 3], a3);
            }
            float v = (a0 + a1) + (a2 + a3) + bias_s[c0 + cc];
            v = (v > 0.f) ? v : expm1f(v);          // ELU
            r[cc] = dn * v;                          // pre-scale for next layer
        }
        __half2 pk[4];
        pk[0] = __float22half2_rn(make_float2(r[0], r[1]));
        pk[1] = __float22half2_rn(make_float2(r[2], r[3]));
        pk[2] = __float22half2_rn(make_float2(r[4], r[5]));
        pk[3] = __float22half2_rn(make_float2(r[6], r[7]));
        *reinterpret_cast<float4*>(gout + (size_t)gnode2 * 64 + c0) =
            *reinterpret_cast<float4*>(pk);
    }
}

// ------------- fused layer 4: aggregate -> GEMM40 -> log_softmax -> d_out
// Phase 2 map: node = wave*8 + (lane>>3), slice = lane&7 (5 classes each);
// softmax reduce over the node's 8 slices via shfl_xor(1,2,4).
__global__ __launch_bounds__(256) void layer4_fused_kernel(const __half* __restrict__ gin,
                                                           const float* __restrict__ dis,
                                                           const int* __restrict__ offsets,
                                                           const int2* __restrict__ pairs,
                                                           const float* __restrict__ W,
                                                           const float* __restrict__ b,
                                                           float* __restrict__ out, int n) {
    __shared__ __half2 rows[32][33];
    __shared__ __half2 WT[40][33];
    __shared__ float bias_s[40];
    for (int idx = threadIdx.x; idx < 40 * 32; idx += 256) {
        int c = idx % 40, k2 = idx / 40;
        WT[c][k2] = __float22half2_rn(make_float2(W[(2 * k2) * 40 + c],
                                                  W[(2 * k2 + 1) * 40 + c]));
    }
    if (threadIdx.x < 40) bias_s[threadIdx.x] = b[threadIdx.x];
    __syncthreads();

    int tid = threadIdx.x;
    phase1_agg(gin, dis, offsets, pairs, rows, n, tid, blockIdx.x * 32);
    wave_lds_fence();

    int lane  = tid & 63, wave = tid >> 6;
    int node2 = wave * 8 + (lane >> 3);
    int slice = lane & 7;                  // classes [5*slice, 5*slice+5)
    int gnode2 = blockIdx.x * 32 + node2;

    float r[5];
    float mp = -__builtin_inff();
    if (gnode2 < n) {
        __half2 h2[32];
        #pragma unroll
        for (int i = 0; i < 32; ++i) h2[i] = rows[node2][i];
        int c0 = slice * 5;
        #pragma unroll
        for (int cc = 0; cc < 5; ++cc) {
            const __half2* wt = &WT[c0 + cc][0];
            float a0 = 0.f, a1 = 0.f, a2 = 0.f, a3 = 0.f;
            #pragma unroll
            for (int i = 0; i < 8; ++i) {
                a0 = fdot2f(h2[4 * i],     wt[4 * i],     a0);
                a1 = fdot2f(h2[4 * i + 1], wt[4 * i + 1], a1);
                a2 = fdot2f(h2[4 * i + 2], wt[4 * i + 2], a2);
                a3 = fdot2f(h2[4 * i + 3], wt[4 * i + 3], a3);
            }
            r[cc] = (a0 + a1) + (a2 + a3) + bias_s[c0 + cc];
            mp = fmaxf(mp, r[cc]);
        }
    }
    // row max/sum over the node's 8 slices (lanes differ only in low 3 bits)
    mp = fmaxf(mp, __shfl_xor(mp, 1));
    mp = fmaxf(mp, __shfl_xor(mp, 2));
    mp = fmaxf(mp, __shfl_xor(mp, 4));
    float sp = 0.f;
    if (gnode2 < n) {
        #pragma unroll
        for (int cc = 0; cc < 5; ++cc) sp += expf(r[cc] - mp);
    }
    sp += __shfl_xor(sp, 1);
    sp += __shfl_xor(sp, 2);
    sp += __shfl_xor(sp, 4);
    if (gnode2 < n) {
        float ls = logf(sp) + mp;
        float* outp = out + (size_t)gnode2 * 40 + slice * 5;
        #pragma unroll
        for (int cc = 0; cc < 5; ++cc) outp[cc] = r[cc] - ls;
    }
}

// ---------------------------------------------------------------- launch

static inline size_t align_up(size_t x, size_t a) { return (x + a - 1) & ~(a - 1); }

extern "C" void kernel_launch(void* const* d_in, const int* in_sizes, int n_in,
                              void* d_out, int out_size, void* d_ws, size_t ws_size,
                              hipStream_t stream) {
    const float* x  = (const float*)d_in[0];
    const int*   ei = (const int*)d_in[1];     // [2][E] flat: src then dst
    const float* ea = (const float*)d_in[2];
    const float* W1 = (const float*)d_in[3];
    const float* b1 = (const float*)d_in[4];
    const float* W2 = (const float*)d_in[5];
    const float* b2 = (const float*)d_in[6];
    const float* W3 = (const float*)d_in[7];
    const float* b3 = (const float*)d_in[8];
    const float* W4 = (const float*)d_in[9];
    const float* b4 = (const float*)d_in[10];

    const int N = in_sizes[0] / 64;
    const int E = in_sizes[1] / 2;

    const int* src = ei;
    const int* dst = ei + E;

    const int nbuck   = (N + NPB - 1) >> NPB_SHIFT;      // 196 for N=100K (<=256)
    const int nblk_ac = (E + CHUNK - 1) / CHUNK;         // 293

    // workspace carve-up
    char* p = (char*)d_ws;
    int*    offsets     = (int*)p;  p += align_up(((size_t)N + 1) * 4, 256);
    int*    bucket_cnt  = (int*)p;  p += align_up(((size_t)nbuck + 1) * 4, 256);
    int*    bucket_base = (int*)p;  p += align_up(((size_t)nbuck + 1) * 4, 256);
    int*    blockbase   = (int*)p;  p += align_up((size_t)nblk_ac * nbuck * 4, 256);
    float*  dis         = (float*)p; p += align_up((size_t)N * 4, 256);
    int2*   pairs       = (int2*)p;  p += align_up(((size_t)E + 8) * 8, 256);
    int2*   temp        = (int2*)p;  p += align_up(((size_t)E + 8) * 8, 256);
    __half* gA          = (__half*)p; p += align_up((size_t)N * 64 * 2, 256);
    __half* gB          = (__half*)p; p += align_up((size_t)N * 64 * 2, 256);
    (void)ws_size;

    const int nb_g16 = (N + 15) / 16;
    const int nb_f   = (N + 31) / 32;

    // --- CSR build (two-level counting sort, LDS-privatized) ---
    bucket_init_kernel<<<1, 256, 0, stream>>>(bucket_cnt, nbuck);
    bucket_count_kernel<<<nblk_ac, 256, 0, stream>>>(dst, bucket_cnt, blockbase, nbuck, E);
    bucket_scan_kernel<<<1, 64, 0, stream>>>(bucket_cnt, bucket_base, nbuck, E);
    bucket_scatter_kernel<<<nblk_ac, 256, 0, stream>>>(src, dst, ea, bucket_base,
                                                       blockbase, temp, nbuck, E);
    bucket_csr_kernel<<<nbuck, 256, 0, stream>>>(temp, bucket_base, offsets, pairs, N, E);
    rowsum_scale_kernel<<<nb_g16, 256, 0, stream>>>(offsets, pairs, x, dis, gA, N);

    // --- layers 1..3 fused (aggregate -> GEMM64+ELU -> fp16), wave-autonomous ---
    layer_fused_kernel<<<nb_f, 256, 0, stream>>>(gA, dis, offsets, pairs, W1, b1, gB, N);
    layer_fused_kernel<<<nb_f, 256, 0, stream>>>(gB, dis, offsets, pairs, W2, b2, gA, N);
    layer_fused_kernel<<<nb_f, 256, 0, stream>>>(gA, dis, offsets, pairs, W3, b3, gB, N);

    // --- layer 4 fused: aggregate -> GEMM40 -> log_softmax -> d_out ---
    layer4_fused_kernel<<<nb_f, 256, 0, stream>>>(gB, dis, offsets, pairs, W4, b4,
                                                  (float*)d_out, N);
}